// Round 15
// baseline (65.966 us; speedup 1.0000x reference)
//
#include <hip/hip_runtime.h>
#include <math.h>

#define DIMC 768
#define BATCH 16
#define HWSZ 1024
#define NT 32

// out layout: result [16*32*768] | p [16*32*768] | mask [16*32*1024]
#define OUT_P_OFF    393216
#define OUT_MASK_OFF 786432

typedef float v4f __attribute__((ext_vector_type(4)));

// ---------------- K0: transpose pww -> wt[c][t]; pack per-channel params ---
// pk[c][12] = { dw[0..8], dw_bias, bn_scale, bn_shift } (48B rows, 16B-aligned)
__global__ __launch_bounds__(256) void k0_prep(
    const float* __restrict__ pww,
    const float* __restrict__ dww, const float* __restrict__ dwb,
    const float* __restrict__ bnw, const float* __restrict__ bnb,
    const float* __restrict__ bnm, const float* __restrict__ bnv,
    float* __restrict__ wt, float* __restrict__ pk)
{
    int i = blockIdx.x * 256 + threadIdx.x;
    if (i < 24576) wt[i] = pww[(i & 31) * DIMC + (i >> 5)];
    int c = i - 24576;
    if (c >= 0 && c < DIMC) {
        float* o = pk + c * 12;
#pragma unroll
        for (int j = 0; j < 9; ++j) o[j] = dww[c * 9 + j];
        o[9] = dwb[c];
        float scale = bnw[c] * rsqrtf(bnv[c] + 1e-5f);
        o[10] = scale;
        o[11] = bnb[c] - bnm[c] * scale;
    }
}

// ---------------- KF: fused BN + dw3x3 + hardswish + pointwise partials ----
// round-7 pipeline, VERTICAL-2 strips: lane owns output rows (gr, gr+1) at
// one column -> 12 ds_reads per 2 conv evals (6/eval vs 9/eval). Block =
// 16 rows x 32 cols, 256 thr. grid (2, 32, 16) = 1024 blocks = 16 waves/CU.
template<int CHPB>
__global__ __launch_bounds__(256) void kf_fused(
    const float* __restrict__ x,
    const float* __restrict__ wt, const float* __restrict__ pk,
    float* __restrict__ partials)
{
    const int b   = blockIdx.z;
    const int scc = blockIdx.y;
    const int cb0 = scc * CHPB;
    const int r0  = blockIdx.x * 16;          // first output row (0 or 16)
    const int tid = threadIdx.x;
    const int rp  = tid >> 5;                 // row pair 0..7
    const int col = tid & 31;

    __shared__ float st[2][612];              // 18x34 zero-padded halo tiles
    for (int i = tid; i < 1224; i += 256) ((float*)st)[i] = 0.0f;

    // staging geometry: slots tid, tid+256, tid+512(<612) over [18][34]
    const int i1  = tid + 256;
    const int i2  = tid + 512;
    const int sr0 = tid / 34, sc0 = tid - sr0 * 34;
    const int sr1 = i1 / 34,  sc1 = i1 - sr1 * 34;
    const int sr2 = i2 / 34,  sc2 = i2 - sr2 * 34;
    const int rr0 = r0 - 1 + sr0, cl0 = sc0 - 1;
    const int rr1 = r0 - 1 + sr1, cl1 = sc1 - 1;
    const int rr2 = r0 - 1 + sr2, cl2 = sc2 - 1;
    const bool va = rr0 >= 0 && rr0 < 32 && cl0 >= 0 && cl0 < 32;
    const bool vb = rr1 >= 0 && rr1 < 32 && cl1 >= 0 && cl1 < 32;
    const bool vc = (i2 < 612) && rr2 >= 0 && rr2 < 32 && cl2 >= 0 && cl2 < 32;
    const int  oa = rr0 * 32 + cl0, ob = rr1 * 32 + cl1, oc = rr2 * 32 + cl2;

    const float* xb  = x  + (size_t)(b * DIMC + cb0) * HWSZ;
    const float* pkb = pk + (size_t)cb0 * 12;
    const float* wtb = wt + (size_t)cb0 * NT;

    // prologue: stage ch0 to LDS; issue ch1, ch2 into registers
    {
        float sc = pkb[10], sh = pkb[11];
        if (va) st[0][tid] = fmaf(xb[oa], sc, sh);
        if (vb) st[0][i1]  = fmaf(xb[ob], sc, sh);
        if (vc) st[0][i2]  = fmaf(xb[oc], sc, sh);
    }
    float g1a = 0.f, g1b = 0.f, g1c = 0.f;
    float g2a = 0.f, g2b = 0.f, g2c = 0.f;
    if (va) g1a = xb[(size_t)1 * HWSZ + oa];
    if (vb) g1b = xb[(size_t)1 * HWSZ + ob];
    if (vc) g1c = xb[(size_t)1 * HWSZ + oc];
    if (va) g2a = xb[(size_t)2 * HWSZ + oa];
    if (vb) g2b = xb[(size_t)2 * HWSZ + ob];
    if (vc) g2c = xb[(size_t)2 * HWSZ + oc];
    __syncthreads();

    v4f A0 = {0,0,0,0}, A1 = {0,0,0,0}, A2 = {0,0,0,0}, A3 = {0,0,0,0};
    v4f A4 = {0,0,0,0}, A5 = {0,0,0,0}, A6 = {0,0,0,0}, A7 = {0,0,0,0};
    v4f B0 = {0,0,0,0}, B1 = {0,0,0,0}, B2 = {0,0,0,0}, B3 = {0,0,0,0};
    v4f B4 = {0,0,0,0}, B5 = {0,0,0,0}, B6 = {0,0,0,0}, B7 = {0,0,0,0};
    const int base = (rp << 1) * 34 + col;    // tile row 2*rp, tile col = col

    for (int k = 0; k < CHPB; ++k) {
        const float* S = &st[k & 1][base];

        // issue loads for channel k+3 (consumed 2 barriers later)
        float g3a = 0.f, g3b = 0.f, g3c = 0.f;
        if (k + 3 < CHPB) {
            if (va) g3a = xb[(size_t)(k + 3) * HWSZ + oa];
            if (vb) g3b = xb[(size_t)(k + 3) * HWSZ + ob];
            if (vc) g3c = xb[(size_t)(k + 3) * HWSZ + oc];
        }

        // 12 LDS taps cover rows gr-1..gr+2
        const float t00 = S[  0], t01 = S[  1], t02 = S[  2];
        const float t10 = S[ 34], t11 = S[ 35], t12 = S[ 36];
        const float t20 = S[ 68], t21 = S[ 69], t22 = S[ 70];
        const float t30 = S[102], t31 = S[103], t32 = S[104];

        // depthwise 3x3 + hardswish for both rows (params uniform s_load)
        const float* pr = pkb + k * 12;
        v4f P0 = *(const v4f*)(pr + 0);
        v4f P1 = *(const v4f*)(pr + 4);
        v4f P2 = *(const v4f*)(pr + 8);       // {w8, dwb, scale, shift}
        float s0 = P2.y, s1 = P2.y;
        s0 = fmaf(P0.x, t00, s0); s1 = fmaf(P0.x, t10, s1);
        s0 = fmaf(P0.y, t01, s0); s1 = fmaf(P0.y, t11, s1);
        s0 = fmaf(P0.z, t02, s0); s1 = fmaf(P0.z, t12, s1);
        s0 = fmaf(P0.w, t10, s0); s1 = fmaf(P0.w, t20, s1);
        s0 = fmaf(P1.x, t11, s0); s1 = fmaf(P1.x, t21, s1);
        s0 = fmaf(P1.y, t12, s0); s1 = fmaf(P1.y, t22, s1);
        s0 = fmaf(P1.z, t20, s0); s1 = fmaf(P1.z, t30, s1);
        s0 = fmaf(P1.w, t21, s0); s1 = fmaf(P1.w, t31, s1);
        s0 = fmaf(P2.x, t22, s0); s1 = fmaf(P2.x, t32, s1);
        float c0 = fminf(fmaxf(s0 + 3.0f, 0.0f), 6.0f);
        float c1 = fminf(fmaxf(s1 + 3.0f, 0.0f), 6.0f);
        float h0 = s0 * c0 * (1.0f / 6.0f);
        float h1 = s1 * c1 * (1.0f / 6.0f);

        // pointwise: 32 token FMAs per row (weights uniform)
        const float* wr = wtb + k * NT;
        v4f hv0 = {h0, h0, h0, h0}, hv1 = {h1, h1, h1, h1};
        v4f w0 = *(const v4f*)(wr +  0), w1 = *(const v4f*)(wr +  4);
        v4f w2 = *(const v4f*)(wr +  8), w3 = *(const v4f*)(wr + 12);
        v4f w4 = *(const v4f*)(wr + 16), w5 = *(const v4f*)(wr + 20);
        v4f w6 = *(const v4f*)(wr + 24), w7 = *(const v4f*)(wr + 28);
        A0 = __builtin_elementwise_fma(hv0, w0, A0); B0 = __builtin_elementwise_fma(hv1, w0, B0);
        A1 = __builtin_elementwise_fma(hv0, w1, A1); B1 = __builtin_elementwise_fma(hv1, w1, B1);
        A2 = __builtin_elementwise_fma(hv0, w2, A2); B2 = __builtin_elementwise_fma(hv1, w2, B2);
        A3 = __builtin_elementwise_fma(hv0, w3, A3); B3 = __builtin_elementwise_fma(hv1, w3, B3);
        A4 = __builtin_elementwise_fma(hv0, w4, A4); B4 = __builtin_elementwise_fma(hv1, w4, B4);
        A5 = __builtin_elementwise_fma(hv0, w5, A5); B5 = __builtin_elementwise_fma(hv1, w5, B5);
        A6 = __builtin_elementwise_fma(hv0, w6, A6); B6 = __builtin_elementwise_fma(hv1, w6, B6);
        A7 = __builtin_elementwise_fma(hv0, w7, A7); B7 = __builtin_elementwise_fma(hv1, w7, B7);

        // late BN + LDS write of channel k+1 (loaded 2 iters ago)
        if (k + 1 < CHPB) {
            float sc = pkb[(k + 1) * 12 + 10], sh = pkb[(k + 1) * 12 + 11];
            float* Sn = &st[(k & 1) ^ 1][0];
            if (va) Sn[tid] = fmaf(g1a, sc, sh);
            if (vb) Sn[i1]  = fmaf(g1b, sc, sh);
            if (vc) Sn[i2]  = fmaf(g1c, sc, sh);
        }
        g1a = g2a; g1b = g2b; g1c = g2c;
        g2a = g3a; g2b = g3b; g2c = g3c;
        __syncthreads();
    }

    // epilogue: row gr at pos0, row gr+1 at pos0+32
    const int pos0 = (r0 + (rp << 1)) * 32 + col;
    float* po = partials + ((size_t)(scc * BATCH + b) * NT) * HWSZ + pos0;
#define STV(G, V0, V1) { \
    po[((4*G+0) << 10)]      = V0.x; po[((4*G+1) << 10)]      = V0.y; \
    po[((4*G+2) << 10)]      = V0.z; po[((4*G+3) << 10)]      = V0.w; \
    po[((4*G+0) << 10) + 32] = V1.x; po[((4*G+1) << 10) + 32] = V1.y; \
    po[((4*G+2) << 10) + 32] = V1.z; po[((4*G+3) << 10) + 32] = V1.w; }
    STV(0, A0, B0) STV(1, A1, B1) STV(2, A2, B2) STV(3, A3, B3)
    STV(4, A4, B4) STV(5, A5, B5) STV(6, A6, B6) STV(7, A7, B7)
#undef STV
}

// ---------------- K3a: sum partials -> argmax -> mask + match list ---------
// match[bt*20] = nm; match[bt*20 + 1 + k] = k-th tied position
template<int SCHT>
__global__ __launch_bounds__(256) void k3a_mask(
    const float* __restrict__ partials,
    float* __restrict__ out, int* __restrict__ match)
{
    int bt = blockIdx.x;           // b*32 + t
    int b  = bt >> 5;
    int t  = bt & 31;
    int tid = threadIdx.x;

    const float4* pp4 = (const float4*)(partials + ((size_t)(b * NT) + t) * HWSZ) + tid;
    float4 acc = make_float4(0.f, 0.f, 0.f, 0.f);
#pragma unroll
    for (int s = 0; s < SCHT; ++s) {
        float4 u = pp4[(size_t)s * (BATCH * NT * HWSZ / 4)];
        acc.x += u.x; acc.y += u.y; acc.z += u.z; acc.w += u.w;
    }

    float m = fmaxf(fmaxf(acc.x, acc.y), fmaxf(acc.z, acc.w));
#pragma unroll
    for (int off = 32; off; off >>= 1)
        m = fmaxf(m, __shfl_xor(m, off));
    __shared__ float wm[4];
    if ((tid & 63) == 0) wm[tid >> 6] = m;
    __syncthreads();
    m = fmaxf(fmaxf(wm[0], wm[1]), fmaxf(wm[2], wm[3]));

    __shared__ int nmatch;
    __shared__ int matchpos[16];
    if (tid == 0) nmatch = 0;
    __syncthreads();

    float* maskp = out + OUT_MASK_OFF + (size_t)bt * HWSZ;
    float4 mask4;
    const float* av = &acc.x;
    float* mv = &mask4.x;
#pragma unroll
    for (int j = 0; j < 4; ++j) {
        int hit = (av[j] == m);
        mv[j] = hit ? 1.0f : 0.0f;
        if (hit) {
            int k = atomicAdd(&nmatch, 1);
            if (k < 16) matchpos[k] = 4 * tid + j;
        }
    }
    ((float4*)maskp)[tid] = mask4;
    __syncthreads();

    int nm = nmatch < 16 ? nmatch : 16;
    if (tid == 0) match[bt * 20] = nm;
    if (tid < nm) match[bt * 20 + 1 + tid] = matchpos[tid];
}

// ---------------- K3b: gather-sum (one channel per lane, max MLP) ----------
__global__ __launch_bounds__(256) void k3b_gather(
    const int* __restrict__ match,
    const float* __restrict__ x, const float* __restrict__ posin,
    const float* __restrict__ bnw, const float* __restrict__ bnb,
    const float* __restrict__ bnm, const float* __restrict__ bnv,
    float* __restrict__ out)
{
    const int bt = blockIdx.y;
    const int b  = bt >> 5;
    const int c  = blockIdx.x * 256 + threadIdx.x;   // < 768

    int nm = match[bt * 20];
    nm = nm < 16 ? nm : 16;

    float scale = bnw[c] * rsqrtf(bnv[c] + 1e-5f);
    float shift = bnb[c] - bnm[c] * scale;

    const float* xc = x     + (size_t)(b * DIMC + c) * HWSZ;
    const float* pc = posin + (size_t)(b * DIMC + c) * HWSZ;

    float rf = 0.0f, rp = 0.0f;
    for (int k = 0; k < nm; ++k) {
        int pos = match[bt * 20 + 1 + k];
        rf += fmaf(xc[pos], scale, shift);
        rp += pc[pos];
    }
    out[(size_t)bt * DIMC + c] = rf;
    out[OUT_P_OFF + (size_t)bt * DIMC + c] = rp;
}

extern "C" void kernel_launch(void* const* d_in, const int* in_sizes, int n_in,
                              void* d_out, int out_size, void* d_ws, size_t ws_size,
                              hipStream_t stream)
{
    const float* x    = (const float*)d_in[0];
    const float* pos  = (const float*)d_in[1];
    const float* bnw  = (const float*)d_in[2];
    const float* bnb  = (const float*)d_in[3];
    const float* bnm  = (const float*)d_in[4];
    const float* bnv  = (const float*)d_in[5];
    const float* dww  = (const float*)d_in[6];
    const float* dwb  = (const float*)d_in[7];
    const float* pww  = (const float*)d_in[8];
    // d_in[9] (pw_bias) unused: constant per (b,t) row -> outputs invariant.
    float* out = (float*)d_out;

    // SCH=32 when workspace allows, else SCH=16 fallback
    const size_t part32 = (size_t)32 * BATCH * NT * HWSZ;   // floats
    const size_t need32 = (part32 + 24576 + 9216 + 10240) * sizeof(float);
    const bool big = ws_size >= need32;
    const size_t partN = (big ? (size_t)32 : (size_t)16) * BATCH * NT * HWSZ;

    float* partials = (float*)d_ws;
    float* wt       = (float*)d_ws + partN;
    float* pk       = wt + 24576;
    int*   match    = (int*)(pk + 9216);

    k0_prep<<<99, 256, 0, stream>>>(pww, dww, dwb, bnw, bnb, bnm, bnv, wt, pk);
    if (big) {
        kf_fused<24><<<dim3(2, 32, BATCH), 256, 0, stream>>>(x, wt, pk, partials);
        k3a_mask<32><<<BATCH * NT, 256, 0, stream>>>(partials, out, match);
    } else {
        kf_fused<48><<<dim3(2, 16, BATCH), 256, 0, stream>>>(x, wt, pk, partials);
        k3a_mask<16><<<BATCH * NT, 256, 0, stream>>>(partials, out, match);
    }
    k3b_gather<<<dim3(3, BATCH * NT), 256, 0, stream>>>(match, x, pos,
                                                        bnw, bnb, bnm, bnv, out);
}

// Round 16
// 63.931 us; speedup vs baseline: 1.0318x; 1.0318x over previous
//
#include <hip/hip_runtime.h>
#include <math.h>

#define DIMC 768
#define BATCH 16
#define HWSZ 1024
#define NT 32

// out layout: result [16*32*768] | p [16*32*768] | mask [16*32*1024]
#define OUT_P_OFF    393216
#define OUT_MASK_OFF 786432

typedef float v4f __attribute__((ext_vector_type(4)));

// ---------------- K0: transpose pww -> wt[c][t]; pack per-channel params ---
// pk[c][12] = { dw[0..8], dw_bias, bn_scale, bn_shift } (48B rows, 16B-aligned)
__global__ __launch_bounds__(256) void k0_prep(
    const float* __restrict__ pww,
    const float* __restrict__ dww, const float* __restrict__ dwb,
    const float* __restrict__ bnw, const float* __restrict__ bnb,
    const float* __restrict__ bnm, const float* __restrict__ bnv,
    float* __restrict__ wt, float* __restrict__ pk)
{
    int i = blockIdx.x * 256 + threadIdx.x;
    if (i < 24576) wt[i] = pww[(i & 31) * DIMC + (i >> 5)];
    int c = i - 24576;
    if (c >= 0 && c < DIMC) {
        float* o = pk + c * 12;
#pragma unroll
        for (int j = 0; j < 9; ++j) o[j] = dww[c * 9 + j];
        o[9] = dwb[c];
        float scale = bnw[c] * rsqrtf(bnv[c] + 1e-5f);
        o[10] = scale;
        o[11] = bnb[c] - bnm[c] * scale;
    }
}

// ---------------- KF: fused BN + dw3x3 + hardswish + pointwise partials ----
// round-7 structure (measured 40 us twice): 256 thr, one position/lane, one
// channel per barrier-iter, LDS double-buffer. NEW: depth-4 register prefetch.
template<int CHPB>
__global__ __launch_bounds__(256) void kf_fused(
    const float* __restrict__ x,
    const float* __restrict__ wt, const float* __restrict__ pk,
    float* __restrict__ partials)
{
    const int b   = blockIdx.z;
    const int scc = blockIdx.y;
    const int cb0 = scc * CHPB;
    const int r0  = blockIdx.x * 8;           // first output row
    const int tid = threadIdx.x;
    const int rl  = tid >> 5;
    const int col = tid & 31;

    __shared__ float st[2][340];              // zero-padded 10x34 halo tiles
    for (int i = tid; i < 680; i += 256) ((float*)st)[i] = 0.0f;

    // staging geometry: slots tid and tid+256 over [10][34]
    const int i1  = tid + 256;
    const int sr0 = tid / 34, sc0 = tid - sr0 * 34;
    const int sr1 = i1 / 34,  sc1 = i1 - sr1 * 34;
    const int rr0 = r0 - 1 + sr0, cl0 = sc0 - 1;
    const int rr1 = r0 - 1 + sr1, cl1 = sc1 - 1;
    const bool va = rr0 >= 0 && rr0 < 32 && cl0 >= 0 && cl0 < 32;
    const bool vb = (i1 < 340) && rr1 >= 0 && rr1 < 32 && cl1 >= 0 && cl1 < 32;
    const int  oa = rr0 * 32 + cl0, ob = rr1 * 32 + cl1;

    const float* xb  = x  + (size_t)(b * DIMC + cb0) * HWSZ;
    const float* pkb = pk + (size_t)cb0 * 12;
    const float* wtb = wt + (size_t)cb0 * NT;

    // prologue: stage ch0 to LDS; issue ch1..ch3 into registers (depth 4)
    {
        float sc = pkb[10], sh = pkb[11];
        if (va) st[0][tid] = fmaf(xb[oa], sc, sh);
        if (vb) st[0][i1]  = fmaf(xb[ob], sc, sh);
    }
    float g1a = 0.f, g1b = 0.f, g2a = 0.f, g2b = 0.f, g3a = 0.f, g3b = 0.f;
    if (va) g1a = xb[(size_t)1 * HWSZ + oa];
    if (vb) g1b = xb[(size_t)1 * HWSZ + ob];
    if (va) g2a = xb[(size_t)2 * HWSZ + oa];
    if (vb) g2b = xb[(size_t)2 * HWSZ + ob];
    if (va) g3a = xb[(size_t)3 * HWSZ + oa];
    if (vb) g3b = xb[(size_t)3 * HWSZ + ob];
    __syncthreads();

    v4f A0 = {0,0,0,0}, A1 = {0,0,0,0}, A2 = {0,0,0,0}, A3 = {0,0,0,0};
    v4f A4 = {0,0,0,0}, A5 = {0,0,0,0}, A6 = {0,0,0,0}, A7 = {0,0,0,0};
    const int base = rl * 34 + col;

    for (int k = 0; k < CHPB; ++k) {
        const float* S = &st[k & 1][base];

        // issue loads for channel k+4 (consumed 3 barriers later)
        float g4a = 0.f, g4b = 0.f;
        if (k + 4 < CHPB) {
            if (va) g4a = xb[(size_t)(k + 4) * HWSZ + oa];
            if (vb) g4b = xb[(size_t)(k + 4) * HWSZ + ob];
        }

        // depthwise 3x3 + hardswish (params via uniform s_load)
        const float* pr = pkb + k * 12;
        v4f P0 = *(const v4f*)(pr + 0);
        v4f P1 = *(const v4f*)(pr + 4);
        v4f P2 = *(const v4f*)(pr + 8);       // {w8, dwb, scale, shift}
        float r = P2.y;
        r = fmaf(P0.x, S[ 0], r);
        r = fmaf(P0.y, S[ 1], r);
        r = fmaf(P0.z, S[ 2], r);
        r = fmaf(P0.w, S[34], r);
        r = fmaf(P1.x, S[35], r);
        r = fmaf(P1.y, S[36], r);
        r = fmaf(P1.z, S[68], r);
        r = fmaf(P1.w, S[69], r);
        r = fmaf(P2.x, S[70], r);
        float clp = fminf(fmaxf(r + 3.0f, 0.0f), 6.0f);
        float hs  = r * clp * (1.0f / 6.0f);

        // pointwise: 32 token FMAs (weights uniform)
        const float* wr = wtb + k * NT;
        v4f hv = {hs, hs, hs, hs};
        A0 = __builtin_elementwise_fma(hv, *(const v4f*)(wr +  0), A0);
        A1 = __builtin_elementwise_fma(hv, *(const v4f*)(wr +  4), A1);
        A2 = __builtin_elementwise_fma(hv, *(const v4f*)(wr +  8), A2);
        A3 = __builtin_elementwise_fma(hv, *(const v4f*)(wr + 12), A3);
        A4 = __builtin_elementwise_fma(hv, *(const v4f*)(wr + 16), A4);
        A5 = __builtin_elementwise_fma(hv, *(const v4f*)(wr + 20), A5);
        A6 = __builtin_elementwise_fma(hv, *(const v4f*)(wr + 24), A6);
        A7 = __builtin_elementwise_fma(hv, *(const v4f*)(wr + 28), A7);

        // late BN + LDS write of channel k+1 (loaded 3 iters ago)
        if (k + 1 < CHPB) {
            float sc = pkb[(k + 1) * 12 + 10], sh = pkb[(k + 1) * 12 + 11];
            float* Sn = &st[(k & 1) ^ 1][0];
            if (va) Sn[tid] = fmaf(g1a, sc, sh);
            if (vb) Sn[i1]  = fmaf(g1b, sc, sh);
        }
        g1a = g2a; g1b = g2b;
        g2a = g3a; g2b = g3b;
        g3a = g4a; g3b = g4b;
        __syncthreads();
    }

    float* po = partials + ((size_t)(scc * BATCH + b) * NT) * HWSZ
              + blockIdx.x * 256 + tid;
    po[ 0 << 10] = A0.x; po[ 1 << 10] = A0.y; po[ 2 << 10] = A0.z; po[ 3 << 10] = A0.w;
    po[ 4 << 10] = A1.x; po[ 5 << 10] = A1.y; po[ 6 << 10] = A1.z; po[ 7 << 10] = A1.w;
    po[ 8 << 10] = A2.x; po[ 9 << 10] = A2.y; po[10 << 10] = A2.z; po[11 << 10] = A2.w;
    po[12 << 10] = A3.x; po[13 << 10] = A3.y; po[14 << 10] = A3.z; po[15 << 10] = A3.w;
    po[16 << 10] = A4.x; po[17 << 10] = A4.y; po[18 << 10] = A4.z; po[19 << 10] = A4.w;
    po[20 << 10] = A5.x; po[21 << 10] = A5.y; po[22 << 10] = A5.z; po[23 << 10] = A5.w;
    po[24 << 10] = A6.x; po[25 << 10] = A6.y; po[26 << 10] = A6.z; po[27 << 10] = A6.w;
    po[28 << 10] = A7.x; po[29 << 10] = A7.y; po[30 << 10] = A7.z; po[31 << 10] = A7.w;
}

// ---------------- K3: sum partials -> argmax mask -> ILP gather ------------
// monolithic (one block per bt). Gather phase: nm is block-uniform; fast
// path nm==1 issues all 6 loads (3 channels x {x,pos}) as independent chains.
template<int SCHT>
__global__ __launch_bounds__(256) void k3_mask_gather(
    const float* __restrict__ partials,
    const float* __restrict__ x, const float* __restrict__ posin,
    const float* __restrict__ bnw, const float* __restrict__ bnb,
    const float* __restrict__ bnm, const float* __restrict__ bnv,
    float* __restrict__ out)
{
    int bt = blockIdx.x;           // b*32 + t
    int b  = bt >> 5;
    int t  = bt & 31;
    int tid = threadIdx.x;

    const float4* pp4 = (const float4*)(partials + ((size_t)(b * NT) + t) * HWSZ) + tid;
    float4 acc = make_float4(0.f, 0.f, 0.f, 0.f);
#pragma unroll
    for (int s = 0; s < SCHT; ++s) {
        float4 u = pp4[(size_t)s * (BATCH * NT * HWSZ / 4)];
        acc.x += u.x; acc.y += u.y; acc.z += u.z; acc.w += u.w;
    }

    float m = fmaxf(fmaxf(acc.x, acc.y), fmaxf(acc.z, acc.w));
#pragma unroll
    for (int off = 32; off; off >>= 1)
        m = fmaxf(m, __shfl_xor(m, off));
    __shared__ float wm[4];
    if ((tid & 63) == 0) wm[tid >> 6] = m;
    __syncthreads();
    m = fmaxf(fmaxf(wm[0], wm[1]), fmaxf(wm[2], wm[3]));

    __shared__ int nmatch;
    __shared__ int matchpos[16];
    if (tid == 0) nmatch = 0;
    __syncthreads();

    float* maskp = out + OUT_MASK_OFF + (size_t)bt * HWSZ;
    float4 mask4;
    const float* av = &acc.x;
    float* mv = &mask4.x;
#pragma unroll
    for (int j = 0; j < 4; ++j) {
        int hit = (av[j] == m);
        mv[j] = hit ? 1.0f : 0.0f;
        if (hit) {
            int k = atomicAdd(&nmatch, 1);
            if (k < 16) matchpos[k] = 4 * tid + j;
        }
    }
    ((float4*)maskp)[tid] = mask4;
    __syncthreads();
    int nm = nmatch < 16 ? nmatch : 16;

    const float* xb = x + (size_t)b * DIMC * HWSZ;
    const float* pb = posin + (size_t)b * DIMC * HWSZ;
    const int c0 = tid, c1 = tid + 256, c2 = tid + 512;

    // BN params for the 3 channels (independent, coalesced)
    float sc0 = bnw[c0] * rsqrtf(bnv[c0] + 1e-5f), sh0 = bnb[c0] - bnm[c0] * sc0;
    float sc1 = bnw[c1] * rsqrtf(bnv[c1] + 1e-5f), sh1 = bnb[c1] - bnm[c1] * sc1;
    float sc2 = bnw[c2] * rsqrtf(bnv[c2] + 1e-5f), sh2 = bnb[c2] - bnm[c2] * sc2;

    float rf0, rf1, rf2, rp0, rp1, rp2;
    if (nm == 1) {                 // dominant case: all 6 loads independent
        int pos = matchpos[0];
        float x0 = xb[(size_t)c0 * HWSZ + pos];
        float x1 = xb[(size_t)c1 * HWSZ + pos];
        float x2 = xb[(size_t)c2 * HWSZ + pos];
        float p0 = pb[(size_t)c0 * HWSZ + pos];
        float p1 = pb[(size_t)c1 * HWSZ + pos];
        float p2 = pb[(size_t)c2 * HWSZ + pos];
        rf0 = fmaf(x0, sc0, sh0); rp0 = p0;
        rf1 = fmaf(x1, sc1, sh1); rp1 = p1;
        rf2 = fmaf(x2, sc2, sh2); rp2 = p2;
    } else {
        rf0 = rf1 = rf2 = rp0 = rp1 = rp2 = 0.0f;
        for (int k = 0; k < nm; ++k) {
            int pos = matchpos[k];
            rf0 += fmaf(xb[(size_t)c0 * HWSZ + pos], sc0, sh0);
            rf1 += fmaf(xb[(size_t)c1 * HWSZ + pos], sc1, sh1);
            rf2 += fmaf(xb[(size_t)c2 * HWSZ + pos], sc2, sh2);
            rp0 += pb[(size_t)c0 * HWSZ + pos];
            rp1 += pb[(size_t)c1 * HWSZ + pos];
            rp2 += pb[(size_t)c2 * HWSZ + pos];
        }
    }
    out[(size_t)bt * DIMC + c0] = rf0;
    out[(size_t)bt * DIMC + c1] = rf1;
    out[(size_t)bt * DIMC + c2] = rf2;
    out[OUT_P_OFF + (size_t)bt * DIMC + c0] = rp0;
    out[OUT_P_OFF + (size_t)bt * DIMC + c1] = rp1;
    out[OUT_P_OFF + (size_t)bt * DIMC + c2] = rp2;
}

extern "C" void kernel_launch(void* const* d_in, const int* in_sizes, int n_in,
                              void* d_out, int out_size, void* d_ws, size_t ws_size,
                              hipStream_t stream)
{
    const float* x    = (const float*)d_in[0];
    const float* pos  = (const float*)d_in[1];
    const float* bnw  = (const float*)d_in[2];
    const float* bnb  = (const float*)d_in[3];
    const float* bnm  = (const float*)d_in[4];
    const float* bnv  = (const float*)d_in[5];
    const float* dww  = (const float*)d_in[6];
    const float* dwb  = (const float*)d_in[7];
    const float* pww  = (const float*)d_in[8];
    // d_in[9] (pw_bias) unused: constant per (b,t) row -> outputs invariant.
    float* out = (float*)d_out;

    // SCH=32 (round-7 measured-best kf) when workspace allows
    const size_t part32 = (size_t)32 * BATCH * NT * HWSZ;   // floats
    const size_t need32 = (part32 + 24576 + 9216) * sizeof(float);
    const bool big = ws_size >= need32;
    const size_t partN = (big ? (size_t)32 : (size_t)16) * BATCH * NT * HWSZ;

    float* partials = (float*)d_ws;
    float* wt       = (float*)d_ws + partN;
    float* pk       = wt + 24576;

    k0_prep<<<99, 256, 0, stream>>>(pww, dww, dwb, bnw, bnb, bnm, bnv, wt, pk);
    if (big) {
        kf_fused<24><<<dim3(4, 32, BATCH), 256, 0, stream>>>(x, wt, pk, partials);
        k3_mask_gather<32><<<BATCH * NT, 256, 0, stream>>>(partials, x, pos,
                                                           bnw, bnb, bnm, bnv, out);
    } else {
        kf_fused<48><<<dim3(4, 16, BATCH), 256, 0, stream>>>(x, wt, pk, partials);
        k3_mask_gather<16><<<BATCH * NT, 256, 0, stream>>>(partials, x, pos,
                                                           bnw, bnb, bnm, bnv, out);
    }
}